// Round 12
// baseline (13295.282 us; speedup 1.0000x reference)
//
#include <hip/hip_runtime.h>
#include <math.h>
#include <limits.h>

#define B32 32
#define KD 1024
#define HID 1024
#define VOC 32000
#define NL 3
#define TN 128
#define BKC 32
#define ASTR 36
#define WSTR 68
#define GEMM_THREADS 128
#define KS_GRU 4
#define CANDMAX 64

typedef __attribute__((ext_vector_type(8))) short bf16x8;
typedef __attribute__((ext_vector_type(8))) unsigned short u16x8;
typedef __attribute__((ext_vector_type(16))) float f32x16;

__device__ __forceinline__ float sigmoidf_(float x) { return 1.0f / (1.0f + expf(-x)); }

__device__ __forceinline__ unsigned short f2bf(float f) {
    unsigned u = __float_as_uint(f);
    u = u + 0x7fffu + ((u >> 16) & 1u);
    return (unsigned short)(u >> 16);
}
__device__ __forceinline__ float bf2f(unsigned short h) {
    return __uint_as_float(((unsigned)h) << 16);
}
__device__ __forceinline__ f32x16 MF(bf16x8 a, bf16x8 b, f32x16 c) {
    return __builtin_amdgcn_mfma_f32_32x32x16_bf16(a, b, c, 0, 0, 0);
}

// ---------------- one-time pack: fp32 [ntiles*32][1024] -> fragment-packed hi (+optional lo)
__global__ __launch_bounds__(256)
void pack_w(const float* __restrict__ src, unsigned short* __restrict__ hi,
            unsigned short* __restrict__ lo, long ntiles)
{
    long tid = (long)blockIdx.x * 256 + threadIdx.x;
    long total = ntiles * 4096;
    if (tid >= total) return;
    long tile = tid >> 12;
    int r = (int)(tid & 4095);
    int k8 = r >> 5, c = r & 31;
    const float* s = src + ((size_t)tile * 32 + c) * KD + k8 * 8;
    float4 f0 = ((const float4*)s)[0];
    float4 f1 = ((const float4*)s)[1];
    float ff[8] = {f0.x, f0.y, f0.z, f0.w, f1.x, f1.y, f1.z, f1.w};
    u16x8 h, l;
#pragma unroll
    for (int j = 0; j < 8; ++j) {
        unsigned short hh = f2bf(ff[j]);
        h[j] = hh;
        l[j] = f2bf(ff[j] - bf2f(hh));
    }
    size_t o = ((size_t)tile << 15) + (size_t)k8 * 256 + (size_t)c * 8;
    *(u16x8*)(hi + o) = h;
    if (lo) *(u16x8*)(lo + o) = l;
}

// ---------------- one-time: max column norm of fcw
__global__ __launch_bounds__(256)
void wnorm_k(const float* __restrict__ fcw, unsigned* __restrict__ wn)
{
    const int tid = threadIdx.x;
    const int r = blockIdx.x * 64 + (tid >> 2);
    const int q = tid & 3;
    const float* row = fcw + (size_t)r * KD + q * 256;
    float s = 0.f;
#pragma unroll 8
    for (int i = 0; i < 64; ++i) {
        float4 v = ((const float4*)row)[i];
        s += v.x * v.x + v.y * v.y + v.z * v.z + v.w * v.w;
    }
    s += __shfl_xor(s, 1);
    s += __shfl_xor(s, 2);
    if (q == 0) atomicMax(wn, __float_as_uint(sqrtf(s)));
}

// ---------------- per-step (32 blocks): exact-argmax fix + emb gather + fragment-pack x
__global__ __launch_bounds__(256)
void fix_gather(const float* __restrict__ out, int tprev, int T,
                const unsigned short* __restrict__ hh, const unsigned short* __restrict__ hl,
                const float* __restrict__ fcw, const float* __restrict__ fcb,
                const unsigned* __restrict__ wn,
                unsigned long long* __restrict__ wbuf,
                const float* __restrict__ emb,
                unsigned short* __restrict__ xhi, unsigned short* __restrict__ xlo,
                int do_fix)
{
    __shared__ float xs[1024];
    __shared__ float cval[CANDMAX];
    __shared__ int   cand[CANDMAX];
    __shared__ int   lcnt, stok;
    __shared__ float wsum[4];
    __shared__ float sred[4];
    const int b = blockIdx.x, tid = threadIdx.x;
    const int wv = tid >> 6, lane = tid & 63;

    if (do_fix) {
        if (tid == 0) lcnt = 0;
        float sq = 0.f;
        for (int k = tid; k < 1024; k += 256) {
            size_t hp = (size_t)(k >> 3) * 256 + (size_t)b * 8 + (k & 7);
            float xv = bf2f(hh[hp]) + bf2f(hl[hp]);
            xs[k] = xv;
            sq += xv * xv;
        }
#pragma unroll
        for (int m = 1; m < 64; m <<= 1) sq += __shfl_xor(sq, m);
        if (lane == 0) sred[wv] = sq;
        __syncthreads();
        float snorm = sred[0] + sred[1] + sred[2] + sred[3];
        unsigned long long key = wbuf[b];
        unsigned hi32 = (unsigned)(key >> 32);
        unsigned fb = (hi32 & 0x80000000u) ? (hi32 & 0x7fffffffu) : ~hi32;
        float m = __uint_as_float(fb);
        float delta = sqrtf(snorm) * __uint_as_float(wn[0]) * (1.01f / 256.0f) + 1e-7f;
        float thr = m - delta;
        const float* orow = out + ((size_t)b * T + tprev) * VOC;
        for (int i = tid; i < VOC / 4; i += 256) {
            float4 v = ((const float4*)orow)[i];
#pragma unroll
            for (int j = 0; j < 4; ++j) {
                float vv = ((const float*)&v)[j];
                if (vv >= thr) {
                    int pos = atomicAdd(&lcnt, 1);
                    if (pos < CANDMAX) cand[pos] = i * 4 + j;
                }
            }
        }
        __syncthreads();
        int nc = lcnt < CANDMAX ? lcnt : CANDMAX;
        for (int c = 0; c < nc; ++c) {
            const float* wr = fcw + (size_t)cand[c] * KD;
            float p = 0.f;
            for (int k = tid; k < 1024; k += 256) p += xs[k] * wr[k];
#pragma unroll
            for (int mm = 1; mm < 64; mm <<= 1) p += __shfl_xor(p, mm);
            if (lane == 0) wsum[wv] = p;
            __syncthreads();
            if (tid == 0) cval[c] = wsum[0] + wsum[1] + wsum[2] + wsum[3] + fcb[cand[c]];
            __syncthreads();
        }
        if (tid == 0) {
            float bv = -INFINITY; int bi = 0;
            for (int c = 0; c < nc; ++c) {
                float v = cval[c]; int ii = cand[c];
                if (c == 0 || v > bv || (v == bv && ii < bi)) { bv = v; bi = ii; }
            }
            stok = bi;
            wbuf[b] = 0ull;
        }
    }
    __syncthreads();
    int tok = do_fix ? stok : 0;
    if (tid < 128) {
        const float* er = emb + (size_t)tok * KD + (size_t)tid * 8;
        float4 f0 = ((const float4*)er)[0];
        float4 f1 = ((const float4*)er)[1];
        float ff[8] = {f0.x, f0.y, f0.z, f0.w, f1.x, f1.y, f1.z, f1.w};
        u16x8 h, l;
#pragma unroll
        for (int j = 0; j < 8; ++j) {
            unsigned short hv = f2bf(ff[j]);
            h[j] = hv;
            l[j] = f2bf(ff[j] - bf2f(hv));
        }
        size_t o = (size_t)tid * 256 + (size_t)b * 8;
        *(u16x8*)(xhi + o) = h;
        *(u16x8*)(xlo + o) = l;
    }
}

// ---------------- gh for ALL layers (hoisted): 384 blocks x 192 thr (3 gate-waves).
// bid = l*128 + jt*4 + ks. Body = R8's 16-iter depth-4 chain (bit-identical summation).
__global__ __launch_bounds__(192)
void gru_gh(const unsigned short* __restrict__ hPh, const unsigned short* __restrict__ hPl,
            const unsigned short* __restrict__ whhPh, const unsigned short* __restrict__ whhPl,
            float* __restrict__ Ggh)
{
    const int bid = blockIdx.x;
    const int l = bid >> 7;
    const int r = bid & 127;
    const int jt = r >> 2, ks = r & 3;
    const int w = threadIdx.x >> 6, lane = threadIdx.x & 63;   // w = gate 0..2
    const size_t PL = (size_t)B32 * KD;
    const unsigned short* Ah = hPh + (size_t)l * PL;
    const unsigned short* Al = hPl + (size_t)l * PL;
    const size_t woff = (size_t)l * 3 * KD * KD + (((size_t)(w * 32 + jt)) << 15);
    const unsigned short* Wh = whhPh + woff;
    const unsigned short* Wl = whhPl + woff;

    const size_t lo8 = (size_t)lane * 8;
    const int kbase = ks * 16;

    f32x16 acc = {0,0,0,0,0,0,0,0,0,0,0,0,0,0,0,0};
    bf16x8 ahB[4], alB[4], whB[4], wlB[4];
#pragma unroll
    for (int i = 0; i < 4; ++i) {
        size_t o = (size_t)(kbase + i) * 512 + lo8;
        ahB[i] = *(const bf16x8*)(Ah + o);
        alB[i] = *(const bf16x8*)(Al + o);
        whB[i] = *(const bf16x8*)(Wh + o);
        wlB[i] = *(const bf16x8*)(Wl + o);
    }
#pragma unroll
    for (int i = 0; i < 16; ++i) {
        const int s = i & 3;
        bf16x8 ah = ahB[s], al = alB[s], wh = whB[s], wl = wlB[s];
        if (i < 12) {
            size_t on = (size_t)(kbase + i + 4) * 512 + lo8;
            ahB[s] = *(const bf16x8*)(Ah + on);
            alB[s] = *(const bf16x8*)(Al + on);
            whB[s] = *(const bf16x8*)(Wh + on);
            wlB[s] = *(const bf16x8*)(Wl + on);
        }
        acc = MF(ah, wh, acc);
        acc = MF(al, wh, acc);
        acc = MF(ah, wl, acc);
    }

    const int kg = lane >> 5, c = lane & 31;
    float* Gb = Ggh + (size_t)((l * 128 + jt * 4 + ks) * 3 + w) * 1024;
#pragma unroll
    for (int rr = 0; rr < 16; ++rr) {
        int b = (rr & 3) + 8 * (rr >> 2) + 4 * kg;
        Gb[b * 32 + c] = acc[rr];
    }
}

// ---------------- gx + fused gates (block-local): 32 blocks x 384 thr (3 gates x 2 k-halves).
// Reads x (packed), writes h[l] in place. Gates tail reads this block's gx from LDS + gh from Ggh.
__global__ __launch_bounds__(384)
void gru_gx_gates(const unsigned short* __restrict__ xh, const unsigned short* __restrict__ xl,
                  const unsigned short* __restrict__ wihh_l, const unsigned short* __restrict__ wihl_l,
                  const float* __restrict__ Ggh_l,
                  const float* __restrict__ bih_l, const float* __restrict__ bhh_l,
                  unsigned short* __restrict__ hh_l, unsigned short* __restrict__ hl_l)
{
    __shared__ float gxs[2][3][B32][32];
    const int jt = blockIdx.x;
    const int tid = threadIdx.x;
    const int w = tid >> 6, lane = tid & 63;
    const int gate = (w < 3) ? w : w - 3;
    const int kh = (w < 3) ? 0 : 1;
    const unsigned short* Wh = wihh_l + (((size_t)(gate * 32 + jt)) << 15);
    const unsigned short* Wl = wihl_l + (((size_t)(gate * 32 + jt)) << 15);
    const size_t lo8 = (size_t)lane * 8;
    const int kbase = kh * 32;

    f32x16 acc = {0,0,0,0,0,0,0,0,0,0,0,0,0,0,0,0};
    bf16x8 ahB[4], alB[4], whB[4], wlB[4];
#pragma unroll
    for (int i = 0; i < 4; ++i) {
        size_t o = (size_t)(kbase + i) * 512 + lo8;
        ahB[i] = *(const bf16x8*)(xh + o);
        alB[i] = *(const bf16x8*)(xl + o);
        whB[i] = *(const bf16x8*)(Wh + o);
        wlB[i] = *(const bf16x8*)(Wl + o);
    }
#pragma unroll
    for (int i = 0; i < 32; ++i) {
        const int s = i & 3;
        bf16x8 ah = ahB[s], al = alB[s], wh = whB[s], wl = wlB[s];
        if (i < 28) {
            size_t on = (size_t)(kbase + i + 4) * 512 + lo8;
            ahB[s] = *(const bf16x8*)(xh + on);
            alB[s] = *(const bf16x8*)(xl + on);
            whB[s] = *(const bf16x8*)(Wh + on);
            wlB[s] = *(const bf16x8*)(Wl + on);
        }
        acc = MF(ah, wh, acc);
        acc = MF(al, wh, acc);
        acc = MF(ah, wl, acc);
    }

    const int kg = lane >> 5, c = lane & 31;
#pragma unroll
    for (int rr = 0; rr < 16; ++rr) {
        int b = (rr & 3) + 8 * (rr >> 2) + 4 * kg;
        gxs[kh][gate][b][c] = acc[rr];
    }
    __syncthreads();

    for (int idx = tid; idx < B32 * 32; idx += 384) {
        int b = idx >> 5, c2 = idx & 31;
        int j = jt * 32 + c2;
        float g0 = gxs[0][0][b][c2] + gxs[1][0][b][c2];
        float g1 = gxs[0][1][b][c2] + gxs[1][1][b][c2];
        float g2 = gxs[0][2][b][c2] + gxs[1][2][b][c2];
        float h0 = 0, h1 = 0, h2 = 0;
#pragma unroll
        for (int ks = 0; ks < 4; ++ks) {
            const float* base = Ggh_l + (size_t)((jt * 4 + ks) * 3) * 1024 + b * 32 + c2;
            h0 += base[0];
            h1 += base[1024];
            h2 += base[2048];
        }
        float rg = sigmoidf_(g0 + bih_l[j] + h0 + bhh_l[j]);
        float zg = sigmoidf_(g1 + bih_l[KD + j] + h1 + bhh_l[KD + j]);
        float ng = tanhf(g2 + bih_l[2 * KD + j] + rg * (h2 + bhh_l[2 * KD + j]));
        size_t hp = (size_t)(j >> 3) * 256 + (size_t)b * 8 + (j & 7);
        float hold = bf2f(hh_l[hp]) + bf2f(hl_l[hp]);
        float hnew = (1.0f - zg) * ng + zg * hold;
        unsigned short hh2 = f2bf(hnew);
        hh_l[hp] = hh2;
        hl_l[hp] = f2bf(hnew - bf2f(hh2));
    }
}

// ---------------- logits (R8 verbatim): hi-only W, 250 blocks x 256 thr, depth-4 prefetch.
__global__ __launch_bounds__(256)
void logits6(const unsigned short* __restrict__ xh, const unsigned short* __restrict__ xl,
             const unsigned short* __restrict__ wh,
             const float* __restrict__ bias, float* __restrict__ out, int t, int T,
             unsigned long long* __restrict__ wbuf)
{
    __shared__ float bvalS[4][B32];
    __shared__ int   bidxS[4][B32];
    const int tid = threadIdx.x;
    const int w = tid >> 6, lane = tid & 63;
    const int tile = blockIdx.x * 4 + w;
    const int n0 = tile * 32;
    const unsigned short* Wt = wh + ((size_t)tile << 15);
    const size_t lo8 = (size_t)lane * 8;

    f32x16 acc = {0,0,0,0,0,0,0,0,0,0,0,0,0,0,0,0};
    bf16x8 ahB[4], alB[4], wvB[4];
#pragma unroll
    for (int i = 0; i < 4; ++i) {
        size_t o = (size_t)i * 512 + lo8;
        ahB[i] = *(const bf16x8*)(xh + o);
        alB[i] = *(const bf16x8*)(xl + o);
        wvB[i] = *(const bf16x8*)(Wt + o);
    }
#pragma unroll
    for (int i = 0; i < 64; ++i) {
        const int s = i & 3;
        bf16x8 ah = ahB[s], al = alB[s], wv = wvB[s];
        if (i < 60) {
            size_t on = (size_t)(i + 4) * 512 + lo8;
            ahB[s] = *(const bf16x8*)(xh + on);
            alB[s] = *(const bf16x8*)(xl + on);
            wvB[s] = *(const bf16x8*)(Wt + on);
        }
        acc = MF(ah, wv, acc);
        acc = MF(al, wv, acc);
    }

    const int kg = lane >> 5, col = lane & 31;
    const float bb = bias[n0 + col];
#pragma unroll
    for (int r = 0; r < 16; ++r) {
        int b = (r & 3) + 8 * (r >> 2) + 4 * kg;
        float v = acc[r] + bb;
        out[((size_t)b * T + t) * VOC + n0 + col] = v;
        float mv = v; int mi = n0 + col;
#pragma unroll
        for (int m = 1; m < 32; m <<= 1) {
            float ov = __shfl_xor(mv, m);
            int   oi = __shfl_xor(mi, m);
            if (ov > mv || (ov == mv && oi < mi)) { mv = ov; mi = oi; }
        }
        if (col == 0) { bvalS[w][b] = mv; bidxS[w][b] = mi; }
    }
    __syncthreads();
    if (tid < B32) {
        int b = tid;
        float mv = bvalS[0][b]; int mi = bidxS[0][b];
#pragma unroll
        for (int q = 1; q < 4; ++q) {
            float v = bvalS[q][b]; int ii = bidxS[q][b];
            if (v > mv || (v == mv && ii < mi)) { mv = v; mi = ii; }
        }
        unsigned u = __float_as_uint(mv);
        u = (u >> 31) ? ~u : (u | 0x80000000u);
        unsigned long long key =
            ((unsigned long long)u << 32) | (unsigned long long)(0xFFFFFFFFu - (unsigned)mi);
        atomicMax(wbuf + b, key);
    }
}

// ================= fp32 fallback (round-1, proven) =================
__global__ __launch_bounds__(GEMM_THREADS)
void gemm_k1024(const float* __restrict__ Ax, const float* __restrict__ Ah,
                const float* __restrict__ emb, const int* __restrict__ tokens, int gather0,
                const float* __restrict__ Wx, const float* __restrict__ Wh,
                const float* __restrict__ bias,
                float* __restrict__ C, int N, int KS)
{
    __shared__ float As[BKC * ASTR];
    __shared__ float Ws[2 * BKC * WSTR];
    const int tid = threadIdx.x;
    const int sel = blockIdx.y;
    const int ks  = blockIdx.x % KS;
    const int nt  = blockIdx.x / KS;
    const int n0  = nt * TN;
    const int klen = KD / KS;
    const int k0 = ks * klen;
    const float* A = sel ? Ah : Ax;
    const float* W = sel ? Wh : Wx;
    const bool gather = (sel == 0) && (gather0 != 0);

    const int tb = tid & 7;
    const int tn = tid >> 3;
    const int s_kq = tid & 7;
    const int s_r  = tid >> 3;

    const float* arow0;
    const float* arow1;
    if (gather) {
        arow0 = emb + (size_t)tokens[s_r] * KD;
        arow1 = emb + (size_t)tokens[s_r + 16] * KD;
    } else {
        arow0 = A + (size_t)s_r * KD;
        arow1 = A + (size_t)(s_r + 16) * KD;
    }
    const float* wrow = W + (size_t)(n0 + s_r) * KD;

    float acc[4][8];
#pragma unroll
    for (int i = 0; i < 4; ++i)
#pragma unroll
        for (int j = 0; j < 8; ++j) acc[i][j] = 0.0f;

    for (int kc = 0; kc < klen; kc += BKC) {
        const int kb = k0 + kc + s_kq * 4;
        float4 a0 = *(const float4*)(arow0 + kb);
        float4 a1 = *(const float4*)(arow1 + kb);
        float4 wv[8];
#pragma unroll
        for (int hh = 0; hh < 8; ++hh)
            wv[hh] = *(const float4*)(wrow + (size_t)hh * 16 * KD + kb);

        __syncthreads();
#pragma unroll
        for (int j = 0; j < 4; ++j) {
            As[(s_kq * 4 + j) * ASTR + s_r]      = ((const float*)&a0)[j];
            As[(s_kq * 4 + j) * ASTR + s_r + 16] = ((const float*)&a1)[j];
        }
#pragma unroll
        for (int hh = 0; hh < 8; ++hh) {
            int row = s_r + hh * 16;
            int half = row >> 6;
            int c = row & 63;
            float* wbase = &Ws[half * BKC * WSTR];
#pragma unroll
            for (int j = 0; j < 4; ++j)
                wbase[(s_kq * 4 + j) * WSTR + c] = ((const float*)&wv[hh])[j];
        }
        __syncthreads();

#pragma unroll
        for (int kk = 0; kk < BKC; ++kk) {
            float4 av = *(const float4*)&As[kk * ASTR + 4 * tb];
            float4 w0 = *(const float4*)&Ws[kk * WSTR + 4 * tn];
            float4 w1 = *(const float4*)&Ws[BKC * WSTR + kk * WSTR + 4 * tn];
#pragma unroll
            for (int i = 0; i < 4; ++i) {
                float a = ((const float*)&av)[i];
                acc[i][0] += a * w0.x; acc[i][1] += a * w0.y;
                acc[i][2] += a * w0.z; acc[i][3] += a * w0.w;
                acc[i][4] += a * w1.x; acc[i][5] += a * w1.y;
                acc[i][6] += a * w1.z; acc[i][7] += a * w1.w;
            }
        }
    }

    const int slice = sel * KS + ks;
    float* Cb = C + (size_t)slice * B32 * N;
    float4 bA = make_float4(0.f, 0.f, 0.f, 0.f), bB = bA;
    if (bias != nullptr && ks == 0) {
        bA = *(const float4*)&bias[n0 + 4 * tn];
        bB = *(const float4*)&bias[n0 + 64 + 4 * tn];
    }
#pragma unroll
    for (int i = 0; i < 4; ++i) {
        int b = 4 * tb + i;
        float4 vA = make_float4(acc[i][0] + bA.x, acc[i][1] + bA.y, acc[i][2] + bA.z, acc[i][3] + bA.w);
        float4 vB = make_float4(acc[i][4] + bB.x, acc[i][5] + bB.y, acc[i][6] + bB.z, acc[i][7] + bB.w);
        *(float4*)&Cb[(size_t)b * N + n0 + 4 * tn]       = vA;
        *(float4*)&Cb[(size_t)b * N + n0 + 64 + 4 * tn]  = vB;
    }
}

__global__ __launch_bounds__(256)
void gru_gates(const float* __restrict__ G,
               const float* __restrict__ bih, const float* __restrict__ bhh,
               float* __restrict__ hl)
{
    int idx = blockIdx.x * 256 + threadIdx.x;
    int b = idx >> 10, j = idx & 1023;
    float xr = 0, xz = 0, xn = 0, hr = 0, hz = 0, hn = 0;
#pragma unroll
    for (int ks = 0; ks < KS_GRU; ++ks) {
        const float* gx = G + ((size_t)ks * B32 + b) * 3072;
        const float* gh = G + ((size_t)(KS_GRU + ks) * B32 + b) * 3072;
        xr += gx[j];        xz += gx[1024 + j];  xn += gx[2048 + j];
        hr += gh[j];        hz += gh[1024 + j];  hn += gh[2048 + j];
    }
    float r = sigmoidf_(xr + bih[j] + hr + bhh[j]);
    float z = sigmoidf_(xz + bih[1024 + j] + hz + bhh[1024 + j]);
    float n = tanhf(xn + bih[2048 + j] + r * (hn + bhh[2048 + j]));
    float ho = hl[idx];
    hl[idx] = (1.0f - z) * n + z * ho;
}

__global__ __launch_bounds__(GEMM_THREADS)
void logits_kernel(const float* __restrict__ x,
                   const float* __restrict__ W, const float* __restrict__ bias,
                   float* __restrict__ out, int t, int T,
                   float* __restrict__ pval, int* __restrict__ pidx)
{
    __shared__ float As[BKC * ASTR];
    __shared__ float Ws[2 * BKC * WSTR];
    __shared__ float rval[B32 * 16];
    __shared__ int   ridx[B32 * 16];
    const int tid = threadIdx.x;
    const int n0 = blockIdx.x * TN;
    const int tb = tid & 7;
    const int tn = tid >> 3;
    const int s_kq = tid & 7;
    const int s_r  = tid >> 3;

    const float* arow0 = x + (size_t)s_r * KD;
    const float* arow1 = x + (size_t)(s_r + 16) * KD;
    const float* wrow  = W + (size_t)(n0 + s_r) * KD;

    float acc[4][8];
#pragma unroll
    for (int i = 0; i < 4; ++i)
#pragma unroll
        for (int j = 0; j < 8; ++j) acc[i][j] = 0.0f;

    for (int kc = 0; kc < KD; kc += BKC) {
        const int kb = kc + s_kq * 4;
        float4 a0 = *(const float4*)(arow0 + kb);
        float4 a1 = *(const float4*)(arow1 + kb);
        float4 wv[8];
#pragma unroll
        for (int hh = 0; hh < 8; ++hh)
            wv[hh] = *(const float4*)(wrow + (size_t)hh * 16 * KD + kb);

        __syncthreads();
#pragma unroll
        for (int j = 0; j < 4; ++j) {
            As[(s_kq * 4 + j) * ASTR + s_r]      = ((const float*)&a0)[j];
            As[(s_kq * 4 + j) * ASTR + s_r + 16] = ((const float*)&a1)[j];
        }
#pragma unroll
        for (int hh = 0; hh < 8; ++hh) {
            int row = s_r + hh * 16;
            int half = row >> 6;
            int c = row & 63;
            float* wbase = &Ws[half * BKC * WSTR];
#pragma unroll
            for (int j = 0; j < 4; ++j)
                wbase[(s_kq * 4 + j) * WSTR + c] = ((const float*)&wv[hh])[j];
        }
        __syncthreads();

#pragma unroll
        for (int kk = 0; kk < BKC; ++kk) {
            float4 av = *(const float4*)&As[kk * ASTR + 4 * tb];
            float4 w0 = *(const float4*)&Ws[kk * WSTR + 4 * tn];
            float4 w1 = *(const float4*)&Ws[BKC * WSTR + kk * WSTR + 4 * tn];
#pragma unroll
            for (int i = 0; i < 4; ++i) {
                float a = ((const float*)&av)[i];
                acc[i][0] += a * w0.x; acc[i][1] += a * w0.y;
                acc[i][2] += a * w0.z; acc[i][3] += a * w0.w;
                acc[i][4] += a * w1.x; acc[i][5] += a * w1.y;
                acc[i][6] += a * w1.z; acc[i][7] += a * w1.w;
            }
        }
    }

    float4 bA = *(const float4*)&bias[n0 + 4 * tn];
    float4 bB = *(const float4*)&bias[n0 + 64 + 4 * tn];

    float bestv[4]; int besti[4];
#pragma unroll
    for (int i = 0; i < 4; ++i) { bestv[i] = -INFINITY; besti[i] = INT_MAX; }

#pragma unroll
    for (int i = 0; i < 4; ++i) {
        int b = 4 * tb + i;
        float* orow = out + ((size_t)b * T + t) * VOC;
        float4 vA = make_float4(acc[i][0] + bA.x, acc[i][1] + bA.y, acc[i][2] + bA.z, acc[i][3] + bA.w);
        float4 vB = make_float4(acc[i][4] + bB.x, acc[i][5] + bB.y, acc[i][6] + bB.z, acc[i][7] + bB.w);
        *(float4*)&orow[n0 + 4 * tn]      = vA;
        *(float4*)&orow[n0 + 64 + 4 * tn] = vB;
#pragma unroll
        for (int j = 0; j < 4; ++j) {
            float v = ((const float*)&vA)[j]; int c = n0 + 4 * tn + j;
            if (v > bestv[i] || (v == bestv[i] && c < besti[i])) { bestv[i] = v; besti[i] = c; }
        }
#pragma unroll
        for (int j = 0; j < 4; ++j) {
            float v = ((const float*)&vB)[j]; int c = n0 + 64 + 4 * tn + j;
            if (v > bestv[i] || (v == bestv[i] && c < besti[i])) { bestv[i] = v; besti[i] = c; }
        }
    }
#pragma unroll
    for (int i = 0; i < 4; ++i) {
        rval[(4 * tb + i) * 16 + tn] = bestv[i];
        ridx[(4 * tb + i) * 16 + tn] = besti[i];
    }
    __syncthreads();
    if (tid < B32) {
        int b = tid;
        float bv = -INFINITY; int bi = INT_MAX;
        for (int q = 0; q < 16; ++q) {
            float v = rval[b * 16 + q]; int ii = ridx[b * 16 + q];
            if (v > bv || (v == bv && ii < bi)) { bv = v; bi = ii; }
        }
        pval[(size_t)blockIdx.x * B32 + b] = bv;
        pidx[(size_t)blockIdx.x * B32 + b] = bi;
    }
}

__global__ __launch_bounds__(256)
void amax_final(const float* __restrict__ pval, const int* __restrict__ pidx,
                int nblk, int* __restrict__ tokens)
{
    int tid = threadIdx.x;
    int b = tid >> 3, l8 = tid & 7;
    float bv = -INFINITY; int bi = INT_MAX;
    for (int q = l8; q < nblk; q += 8) {
        float v = pval[(size_t)q * B32 + b]; int ii = pidx[(size_t)q * B32 + b];
        if (v > bv || (v == bv && ii < bi)) { bv = v; bi = ii; }
    }
#pragma unroll
    for (int off = 1; off < 8; off <<= 1) {
        float ov = __shfl_xor(bv, off);
        int   oi = __shfl_xor(bi, off);
        if (ov > bv || (ov == bv && oi < bi)) { bv = ov; bi = oi; }
    }
    if (l8 == 0) tokens[b] = bi;
}

// ---------------- host ----------------
extern "C" void kernel_launch(void* const* d_in, const int* in_sizes, int n_in,
                              void* d_out, int out_size, void* d_ws, size_t ws_size,
                              hipStream_t stream)
{
    const float* z    = (const float*)d_in[0];
    const float* emb  = (const float*)d_in[1];
    const float* wlat = (const float*)d_in[2];
    const float* blat = (const float*)d_in[3];
    const float* wih  = (const float*)d_in[4];
    const float* whh  = (const float*)d_in[5];
    const float* bih  = (const float*)d_in[6];
    const float* bhh  = (const float*)d_in[7];
    const float* fcw  = (const float*)d_in[8];
    const float* fcb  = (const float*)d_in[9];
    float* out = (float*)d_out;
    const int T = out_size / (B32 * VOC);   // 128

    const size_t NEED = 152000000;
    if (ws_size >= NEED) {
        char* p = (char*)d_ws;
        auto take = [&](size_t bytes) { char* r = p; p += (bytes + 255) & ~(size_t)255; return r; };
        unsigned short* fcwPh = (unsigned short*)take((size_t)VOC * KD * 2);
        unsigned short* wihPh = (unsigned short*)take((size_t)NL * 3 * KD * KD * 2);
        unsigned short* wihPl = (unsigned short*)take((size_t)NL * 3 * KD * KD * 2);
        unsigned short* whhPh = (unsigned short*)take((size_t)NL * 3 * KD * KD * 2);
        unsigned short* whhPl = (unsigned short*)take((size_t)NL * 3 * KD * KD * 2);
        unsigned short* hPh   = (unsigned short*)take((size_t)NL * B32 * KD * 2);
        unsigned short* hPl   = (unsigned short*)take((size_t)NL * B32 * KD * 2);
        unsigned short* xPh   = (unsigned short*)take((size_t)B32 * KD * 2);
        unsigned short* xPl   = (unsigned short*)take((size_t)B32 * KD * 2);
        float* Ggh = (float*)take((size_t)NL * 128 * 3 * 1024 * 4);
        float* h32 = (float*)take((size_t)B32 * NL * KD * 4);
        unsigned long long* wbuf = (unsigned long long*)take(B32 * 8);
        unsigned* wn = (unsigned*)take(256);

        hipMemsetAsync(wbuf, 0, B32 * 8, stream);
        hipMemsetAsync(wn, 0, 4, stream);

        // one-time packing (fcw hi-only; GRU weights hi+lo) + column-norm bound
        {
            long nt_fc = VOC / 32;
            long nt_g  = (long)NL * 3 * KD / 32;
            pack_w<<<(unsigned)((nt_fc * 4096 + 255) / 256), 256, 0, stream>>>(fcw, fcwPh, nullptr, nt_fc);
            pack_w<<<(unsigned)((nt_g * 4096 + 255) / 256), 256, 0, stream>>>(wih, wihPh, wihPl, nt_g);
            pack_w<<<(unsigned)((nt_g * 4096 + 255) / 256), 256, 0, stream>>>(whh, whhPh, whhPl, nt_g);
            wnorm_k<<<VOC / 64, 256, 0, stream>>>(fcw, wn);
        }

        // hidden init (fp32), then pack the 3 [32x1024] planes
        gemm_k1024<<<dim3(NL * KD / TN, 1), GEMM_THREADS, 0, stream>>>(
            z, nullptr, nullptr, nullptr, 0, wlat, nullptr, blat, h32, NL * KD, 1);
        pack_w<<<(unsigned)((3L * 4096 + 255) / 256), 256, 0, stream>>>(h32, hPh, hPl, 3);

        const size_t PL = (size_t)B32 * KD;
        const size_t WL = (size_t)3 * KD * KD;
        for (int t = 0; t < T; ++t) {
            // exact argmax of t-1 + emb gather/pack (reads h[2] pre-update)
            fix_gather<<<B32, 256, 0, stream>>>(
                out, t - 1, T, hPh + 2 * PL, hPl + 2 * PL, fcw, fcb, wn, wbuf,
                emb, xPh, xPl, t > 0 ? 1 : 0);

            // gh for all 3 layers (reads all h planes pre-update)
            gru_gh<<<NL * 128, 192, 0, stream>>>(hPh, hPl, whhPh, whhPl, Ggh);

            // per-layer gx + fused gates (in-place h update)
            for (int l = 0; l < NL; ++l) {
                const unsigned short* xh = (l == 0) ? xPh : hPh + (size_t)(l - 1) * PL;
                const unsigned short* xl = (l == 0) ? xPl : hPl + (size_t)(l - 1) * PL;
                gru_gx_gates<<<32, 384, 0, stream>>>(
                    xh, xl,
                    wihPh + (size_t)l * WL, wihPl + (size_t)l * WL,
                    Ggh + (size_t)l * 128 * 3 * 1024,
                    bih + (size_t)l * 3 * KD, bhh + (size_t)l * 3 * KD,
                    hPh + (size_t)l * PL, hPl + (size_t)l * PL);
            }
            logits6<<<250, 256, 0, stream>>>(
                hPh + 2 * PL, hPl + 2 * PL, fcwPh, fcb, out, t, T, wbuf);
        }
    } else {
        // fallback: round-1 fp32 path
        float* h      = (float*)d_ws;
        float* G      = h + (size_t)B32 * NL * HID;
        float* pval   = G + (size_t)2 * KS_GRU * B32 * NL * HID;
        int*   pidx   = (int*)(pval + (VOC / TN) * B32);
        int*   tokens = (int*)(pidx + (VOC / TN) * B32);

        hipMemsetAsync(tokens, 0, B32 * sizeof(int), stream);

        gemm_k1024<<<dim3(NL * HID / TN, 1), GEMM_THREADS, 0, stream>>>(
            z, nullptr, nullptr, nullptr, 0, wlat, nullptr, blat, h, NL * HID, 1);

        for (int t = 0; t < T; ++t) {
            for (int l = 0; l < NL; ++l) {
                const float* xA = (l == 0) ? nullptr : (h + (size_t)(l - 1) * B32 * HID);
                dim3 gg((NL * HID / TN) * KS_GRU, 2);
                gemm_k1024<<<gg, GEMM_THREADS, 0, stream>>>(
                    xA, h + (size_t)l * B32 * HID, emb, tokens, (l == 0) ? 1 : 0,
                    wih + (size_t)l * NL * HID * KD, whh + (size_t)l * NL * HID * KD,
                    nullptr, G, NL * HID, KS_GRU);
                gru_gates<<<B32 * HID / 256, 256, 0, stream>>>(
                    G, bih + (size_t)l * NL * HID, bhh + (size_t)l * NL * HID,
                    h + (size_t)l * B32 * HID);
            }
            logits_kernel<<<VOC / TN, GEMM_THREADS, 0, stream>>>(
                h + (size_t)2 * B32 * HID, fcw, fcb, out, t, T, pval, pidx);
            amax_final<<<1, 256, 0, stream>>>(pval, pidx, VOC / TN, tokens);
        }
    }
}

// Round 13
// 10807.849 us; speedup vs baseline: 1.2302x; 1.2302x over previous
//
#include <hip/hip_runtime.h>
#include <math.h>
#include <limits.h>

#define B32 32
#define KD 1024
#define HID 1024
#define VOC 32000
#define NL 3
#define TN 128
#define BKC 32
#define ASTR 36
#define WSTR 68
#define GEMM_THREADS 128
#define KS_GRU 4
#define CANDMAX 64

typedef __attribute__((ext_vector_type(8))) short bf16x8;
typedef __attribute__((ext_vector_type(8))) unsigned short u16x8;
typedef __attribute__((ext_vector_type(16))) float f32x16;

__device__ __forceinline__ float sigmoidf_(float x) { return 1.0f / (1.0f + expf(-x)); }

__device__ __forceinline__ unsigned short f2bf(float f) {
    unsigned u = __float_as_uint(f);
    u = u + 0x7fffu + ((u >> 16) & 1u);
    return (unsigned short)(u >> 16);
}
__device__ __forceinline__ float bf2f(unsigned short h) {
    return __uint_as_float(((unsigned)h) << 16);
}
__device__ __forceinline__ f32x16 MF(bf16x8 a, bf16x8 b, f32x16 c) {
    return __builtin_amdgcn_mfma_f32_32x32x16_bf16(a, b, c, 0, 0, 0);
}

// ---------------- one-time pack: fp32 [ntiles*32][1024] -> fragment-packed hi (+optional lo)
__global__ __launch_bounds__(256)
void pack_w(const float* __restrict__ src, unsigned short* __restrict__ hi,
            unsigned short* __restrict__ lo, long ntiles)
{
    long tid = (long)blockIdx.x * 256 + threadIdx.x;
    long total = ntiles * 4096;
    if (tid >= total) return;
    long tile = tid >> 12;
    int r = (int)(tid & 4095);
    int k8 = r >> 5, c = r & 31;
    const float* s = src + ((size_t)tile * 32 + c) * KD + k8 * 8;
    float4 f0 = ((const float4*)s)[0];
    float4 f1 = ((const float4*)s)[1];
    float ff[8] = {f0.x, f0.y, f0.z, f0.w, f1.x, f1.y, f1.z, f1.w};
    u16x8 h, l;
#pragma unroll
    for (int j = 0; j < 8; ++j) {
        unsigned short hh = f2bf(ff[j]);
        h[j] = hh;
        l[j] = f2bf(ff[j] - bf2f(hh));
    }
    size_t o = ((size_t)tile << 15) + (size_t)k8 * 256 + (size_t)c * 8;
    *(u16x8*)(hi + o) = h;
    if (lo) *(u16x8*)(lo + o) = l;
}

// ---------------- one-time: max column norm of fcw
__global__ __launch_bounds__(256)
void wnorm_k(const float* __restrict__ fcw, unsigned* __restrict__ wn)
{
    const int tid = threadIdx.x;
    const int r = blockIdx.x * 64 + (tid >> 2);
    const int q = tid & 3;
    const float* row = fcw + (size_t)r * KD + q * 256;
    float s = 0.f;
#pragma unroll 8
    for (int i = 0; i < 64; ++i) {
        float4 v = ((const float4*)row)[i];
        s += v.x * v.x + v.y * v.y + v.z * v.z + v.w * v.w;
    }
    s += __shfl_xor(s, 1);
    s += __shfl_xor(s, 2);
    if (q == 0) atomicMax(wn, __float_as_uint(sqrtf(s)));
}

// ---------------- packed per-step kernel: blocks 0-31 = exact-argmax fix + emb gather/pack;
// blocks 32..32+NL*128-1 = gh GEMM for all layers (R8's 16-iter ks4 chain, bit-identical).
// No cross-block dependency inside this launch: both halves read only pre-update state.
__global__ __launch_bounds__(256)
void fix_gh(const float* __restrict__ out, int tprev, int T,
            const unsigned short* __restrict__ hPh, const unsigned short* __restrict__ hPl,
            const float* __restrict__ fcw, const float* __restrict__ fcb,
            const unsigned* __restrict__ wn,
            unsigned long long* __restrict__ wbuf,
            const float* __restrict__ emb,
            unsigned short* __restrict__ xhi, unsigned short* __restrict__ xlo,
            const unsigned short* __restrict__ whhPh, const unsigned short* __restrict__ whhPl,
            float* __restrict__ Ggh,
            int do_fix)
{
    const size_t PL = (size_t)B32 * KD;
    if (blockIdx.x >= B32) {
        // ---- gh half ----
        const int bid2 = blockIdx.x - B32;
        const int l = bid2 >> 7;
        const int r = bid2 & 127;
        const int jt = r >> 2, ks = r & 3;
        const int w = threadIdx.x >> 6, lane = threadIdx.x & 63;
        if (w >= 3) return;                    // wave 3 idle
        const unsigned short* Ah = hPh + (size_t)l * PL;
        const unsigned short* Al = hPl + (size_t)l * PL;
        const size_t woff = (size_t)l * 3 * KD * KD + (((size_t)(w * 32 + jt)) << 15);
        const unsigned short* Wh = whhPh + woff;
        const unsigned short* Wl = whhPl + woff;
        const size_t lo8 = (size_t)lane * 8;
        const int kbase = ks * 16;

        f32x16 acc = {0,0,0,0,0,0,0,0,0,0,0,0,0,0,0,0};
        bf16x8 ahB[4], alB[4], whB[4], wlB[4];
#pragma unroll
        for (int i = 0; i < 4; ++i) {
            size_t o = (size_t)(kbase + i) * 512 + lo8;
            ahB[i] = *(const bf16x8*)(Ah + o);
            alB[i] = *(const bf16x8*)(Al + o);
            whB[i] = *(const bf16x8*)(Wh + o);
            wlB[i] = *(const bf16x8*)(Wl + o);
        }
#pragma unroll
        for (int i = 0; i < 16; ++i) {
            const int s = i & 3;
            bf16x8 ah = ahB[s], al = alB[s], wh = whB[s], wl = wlB[s];
            if (i < 12) {
                size_t on = (size_t)(kbase + i + 4) * 512 + lo8;
                ahB[s] = *(const bf16x8*)(Ah + on);
                alB[s] = *(const bf16x8*)(Al + on);
                whB[s] = *(const bf16x8*)(Wh + on);
                wlB[s] = *(const bf16x8*)(Wl + on);
            }
            acc = MF(ah, wh, acc);
            acc = MF(al, wh, acc);
            acc = MF(ah, wl, acc);
        }
        const int kg = lane >> 5, c = lane & 31;
        float* Gb = Ggh + ((size_t)(l * 128 + jt * 4 + ks) * 3 + w) * 1024;
#pragma unroll
        for (int rr = 0; rr < 16; ++rr) {
            int b = (rr & 3) + 8 * (rr >> 2) + 4 * kg;
            Gb[b * 32 + c] = acc[rr];
        }
        return;
    }

    // ---- fix + gather half (R8's fix_gather verbatim; h = layer-2 plane) ----
    __shared__ float xs[1024];
    __shared__ float cval[CANDMAX];
    __shared__ int   cand[CANDMAX];
    __shared__ int   lcnt, stok;
    __shared__ float wsum[4];
    __shared__ float sred[4];
    const unsigned short* hh = hPh + 2 * PL;
    const unsigned short* hl = hPl + 2 * PL;
    const int b = blockIdx.x, tid = threadIdx.x;
    const int wv = tid >> 6, lane = tid & 63;

    if (do_fix) {
        if (tid == 0) lcnt = 0;
        float sq = 0.f;
        for (int k = tid; k < 1024; k += 256) {
            size_t hp = (size_t)(k >> 3) * 256 + (size_t)b * 8 + (k & 7);
            float xv = bf2f(hh[hp]) + bf2f(hl[hp]);
            xs[k] = xv;
            sq += xv * xv;
        }
#pragma unroll
        for (int m = 1; m < 64; m <<= 1) sq += __shfl_xor(sq, m);
        if (lane == 0) sred[wv] = sq;
        __syncthreads();
        float snorm = sred[0] + sred[1] + sred[2] + sred[3];
        unsigned long long key = wbuf[b];
        unsigned hi32 = (unsigned)(key >> 32);
        unsigned fb = (hi32 & 0x80000000u) ? (hi32 & 0x7fffffffu) : ~hi32;
        float m = __uint_as_float(fb);
        float delta = sqrtf(snorm) * __uint_as_float(wn[0]) * (1.01f / 256.0f) + 1e-7f;
        float thr = m - delta;
        const float* orow = out + ((size_t)b * T + tprev) * VOC;
        for (int i = tid; i < VOC / 4; i += 256) {
            float4 v = ((const float4*)orow)[i];
#pragma unroll
            for (int j = 0; j < 4; ++j) {
                float vv = ((const float*)&v)[j];
                if (vv >= thr) {
                    int pos = atomicAdd(&lcnt, 1);
                    if (pos < CANDMAX) cand[pos] = i * 4 + j;
                }
            }
        }
        __syncthreads();
        int nc = lcnt < CANDMAX ? lcnt : CANDMAX;
        for (int c = 0; c < nc; ++c) {
            const float* wr = fcw + (size_t)cand[c] * KD;
            float p = 0.f;
            for (int k = tid; k < 1024; k += 256) p += xs[k] * wr[k];
#pragma unroll
            for (int mm = 1; mm < 64; mm <<= 1) p += __shfl_xor(p, mm);
            if (lane == 0) wsum[wv] = p;
            __syncthreads();
            if (tid == 0) cval[c] = wsum[0] + wsum[1] + wsum[2] + wsum[3] + fcb[cand[c]];
            __syncthreads();
        }
        if (tid == 0) {
            float bv = -INFINITY; int bi = 0;
            for (int c = 0; c < nc; ++c) {
                float v = cval[c]; int ii = cand[c];
                if (c == 0 || v > bv || (v == bv && ii < bi)) { bv = v; bi = ii; }
            }
            stok = bi;
            wbuf[b] = 0ull;
        }
    }
    __syncthreads();
    int tok = do_fix ? stok : 0;
    if (tid < 128) {
        const float* er = emb + (size_t)tok * KD + (size_t)tid * 8;
        float4 f0 = ((const float4*)er)[0];
        float4 f1 = ((const float4*)er)[1];
        float ff[8] = {f0.x, f0.y, f0.z, f0.w, f1.x, f1.y, f1.z, f1.w};
        u16x8 h, l;
#pragma unroll
        for (int j = 0; j < 8; ++j) {
            unsigned short hv = f2bf(ff[j]);
            h[j] = hv;
            l[j] = f2bf(ff[j] - bf2f(hv));
        }
        size_t o = (size_t)tid * 256 + (size_t)b * 8;
        *(u16x8*)(xhi + o) = h;
        *(u16x8*)(xlo + o) = l;
    }
}

// ---------------- gx-only GEMM: 128 blocks x 192 thr (3 gate-waves); R8 chain verbatim.
__global__ __launch_bounds__(192)
void gru_gx(const unsigned short* __restrict__ xhi, const unsigned short* __restrict__ xlo,
            const unsigned short* __restrict__ wihhi, const unsigned short* __restrict__ wihlo,
            float* __restrict__ Gx)
{
    const int bid = blockIdx.x;
    const int jt = bid >> 2, ks4 = bid & 3;
    const int w = threadIdx.x >> 6, lane = threadIdx.x & 63;   // w = gate 0..2
    const size_t woff = ((size_t)(w * 32 + jt)) << 15;
    const unsigned short* Wh = wihhi + woff;
    const unsigned short* Wl = wihlo + woff;
    const size_t lo8 = (size_t)lane * 8;
    const int kbase = ks4 * 16;

    f32x16 acc = {0,0,0,0,0,0,0,0,0,0,0,0,0,0,0,0};
    bf16x8 ahB[4], alB[4], whB[4], wlB[4];
#pragma unroll
    for (int i = 0; i < 4; ++i) {
        size_t o = (size_t)(kbase + i) * 512 + lo8;
        ahB[i] = *(const bf16x8*)(xhi + o);
        alB[i] = *(const bf16x8*)(xlo + o);
        whB[i] = *(const bf16x8*)(Wh + o);
        wlB[i] = *(const bf16x8*)(Wl + o);
    }
#pragma unroll
    for (int i = 0; i < 16; ++i) {
        const int s = i & 3;
        bf16x8 ah = ahB[s], al = alB[s], wh = whB[s], wl = wlB[s];
        if (i < 12) {
            size_t on = (size_t)(kbase + i + 4) * 512 + lo8;
            ahB[s] = *(const bf16x8*)(xhi + on);
            alB[s] = *(const bf16x8*)(xlo + on);
            whB[s] = *(const bf16x8*)(Wh + on);
            wlB[s] = *(const bf16x8*)(Wl + on);
        }
        acc = MF(ah, wh, acc);
        acc = MF(al, wh, acc);
        acc = MF(ah, wl, acc);
    }

    const int kg = lane >> 5, c = lane & 31;
    float* Gb = Gx + ((size_t)((jt * 4 + ks4) * 3 + w)) * 1024;
#pragma unroll
    for (int r = 0; r < 16; ++r) {
        int b = (r & 3) + 8 * (r >> 2) + 4 * kg;
        Gb[b * 32 + c] = acc[r];
    }
}

// ---------------- gates: sum gx + gh partials (R8 accumulator order), in-place packed h update
__global__ __launch_bounds__(256)
void gru_gates3(const float* __restrict__ Gx, const float* __restrict__ Ggh_l,
                const float* __restrict__ bih, const float* __restrict__ bhh,
                unsigned short* __restrict__ hhi, unsigned short* __restrict__ hlo)
{
    int idx = blockIdx.x * 256 + threadIdx.x;   // 32768
    int b = idx >> 10, j = idx & 1023;
    int jt = j >> 5, c = j & 31;
    float s0 = 0, s1 = 0, s2 = 0, s3 = 0, s4 = 0, s5 = 0;
#pragma unroll
    for (int ks = 0; ks < 4; ++ks) {
        const float* bx = Gx    + ((size_t)((jt * 4 + ks) * 3)) * 1024 + b * 32 + c;
        const float* bh = Ggh_l + ((size_t)((jt * 4 + ks) * 3)) * 1024 + b * 32 + c;
        s0 += bx[0];
        s1 += bx[1024];
        s2 += bx[2048];
        s3 += bh[0];
        s4 += bh[1024];
        s5 += bh[2048];
    }
    float rg = sigmoidf_(s0 + bih[j] + s3 + bhh[j]);
    float zg = sigmoidf_(s1 + bih[KD + j] + s4 + bhh[KD + j]);
    float ng = tanhf(s2 + bih[2 * KD + j] + rg * (s5 + bhh[2 * KD + j]));
    size_t hp = (size_t)(j >> 3) * 256 + (size_t)b * 8 + (j & 7);
    float hold = bf2f(hhi[hp]) + bf2f(hlo[hp]);
    float hnew = (1.0f - zg) * ng + zg * hold;
    unsigned short hh = f2bf(hnew);
    hhi[hp] = hh;
    hlo[hp] = f2bf(hnew - bf2f(hh));
}

// ---------------- logits (R8 verbatim): hi-only W, 250 blocks x 256 thr, depth-4 prefetch.
__global__ __launch_bounds__(256)
void logits6(const unsigned short* __restrict__ xh, const unsigned short* __restrict__ xl,
             const unsigned short* __restrict__ wh,
             const float* __restrict__ bias, float* __restrict__ out, int t, int T,
             unsigned long long* __restrict__ wbuf)
{
    __shared__ float bvalS[4][B32];
    __shared__ int   bidxS[4][B32];
    const int tid = threadIdx.x;
    const int w = tid >> 6, lane = tid & 63;
    const int tile = blockIdx.x * 4 + w;
    const int n0 = tile * 32;
    const unsigned short* Wt = wh + ((size_t)tile << 15);
    const size_t lo8 = (size_t)lane * 8;

    f32x16 acc = {0,0,0,0,0,0,0,0,0,0,0,0,0,0,0,0};
    bf16x8 ahB[4], alB[4], wvB[4];
#pragma unroll
    for (int i = 0; i < 4; ++i) {
        size_t o = (size_t)i * 512 + lo8;
        ahB[i] = *(const bf16x8*)(xh + o);
        alB[i] = *(const bf16x8*)(xl + o);
        wvB[i] = *(const bf16x8*)(Wt + o);
    }
#pragma unroll
    for (int i = 0; i < 64; ++i) {
        const int s = i & 3;
        bf16x8 ah = ahB[s], al = alB[s], wv = wvB[s];
        if (i < 60) {
            size_t on = (size_t)(i + 4) * 512 + lo8;
            ahB[s] = *(const bf16x8*)(xh + on);
            alB[s] = *(const bf16x8*)(xl + on);
            wvB[s] = *(const bf16x8*)(Wt + on);
        }
        acc = MF(ah, wv, acc);
        acc = MF(al, wv, acc);
    }

    const int kg = lane >> 5, col = lane & 31;
    const float bb = bias[n0 + col];
#pragma unroll
    for (int r = 0; r < 16; ++r) {
        int b = (r & 3) + 8 * (r >> 2) + 4 * kg;
        float v = acc[r] + bb;
        out[((size_t)b * T + t) * VOC + n0 + col] = v;
        float mv = v; int mi = n0 + col;
#pragma unroll
        for (int m = 1; m < 32; m <<= 1) {
            float ov = __shfl_xor(mv, m);
            int   oi = __shfl_xor(mi, m);
            if (ov > mv || (ov == mv && oi < mi)) { mv = ov; mi = oi; }
        }
        if (col == 0) { bvalS[w][b] = mv; bidxS[w][b] = mi; }
    }
    __syncthreads();
    if (tid < B32) {
        int b = tid;
        float mv = bvalS[0][b]; int mi = bidxS[0][b];
#pragma unroll
        for (int q = 1; q < 4; ++q) {
            float v = bvalS[q][b]; int ii = bidxS[q][b];
            if (v > mv || (v == mv && ii < mi)) { mv = v; mi = ii; }
        }
        unsigned u = __float_as_uint(mv);
        u = (u >> 31) ? ~u : (u | 0x80000000u);
        unsigned long long key =
            ((unsigned long long)u << 32) | (unsigned long long)(0xFFFFFFFFu - (unsigned)mi);
        atomicMax(wbuf + b, key);
    }
}

// ================= fp32 fallback (round-1, proven) =================
__global__ __launch_bounds__(GEMM_THREADS)
void gemm_k1024(const float* __restrict__ Ax, const float* __restrict__ Ah,
                const float* __restrict__ emb, const int* __restrict__ tokens, int gather0,
                const float* __restrict__ Wx, const float* __restrict__ Wh,
                const float* __restrict__ bias,
                float* __restrict__ C, int N, int KS)
{
    __shared__ float As[BKC * ASTR];
    __shared__ float Ws[2 * BKC * WSTR];
    const int tid = threadIdx.x;
    const int sel = blockIdx.y;
    const int ks  = blockIdx.x % KS;
    const int nt  = blockIdx.x / KS;
    const int n0  = nt * TN;
    const int klen = KD / KS;
    const int k0 = ks * klen;
    const float* A = sel ? Ah : Ax;
    const float* W = sel ? Wh : Wx;
    const bool gather = (sel == 0) && (gather0 != 0);

    const int tb = tid & 7;
    const int tn = tid >> 3;
    const int s_kq = tid & 7;
    const int s_r  = tid >> 3;

    const float* arow0;
    const float* arow1;
    if (gather) {
        arow0 = emb + (size_t)tokens[s_r] * KD;
        arow1 = emb + (size_t)tokens[s_r + 16] * KD;
    } else {
        arow0 = A + (size_t)s_r * KD;
        arow1 = A + (size_t)(s_r + 16) * KD;
    }
    const float* wrow = W + (size_t)(n0 + s_r) * KD;

    float acc[4][8];
#pragma unroll
    for (int i = 0; i < 4; ++i)
#pragma unroll
        for (int j = 0; j < 8; ++j) acc[i][j] = 0.0f;

    for (int kc = 0; kc < klen; kc += BKC) {
        const int kb = k0 + kc + s_kq * 4;
        float4 a0 = *(const float4*)(arow0 + kb);
        float4 a1 = *(const float4*)(arow1 + kb);
        float4 wv[8];
#pragma unroll
        for (int hh = 0; hh < 8; ++hh)
            wv[hh] = *(const float4*)(wrow + (size_t)hh * 16 * KD + kb);

        __syncthreads();
#pragma unroll
        for (int j = 0; j < 4; ++j) {
            As[(s_kq * 4 + j) * ASTR + s_r]      = ((const float*)&a0)[j];
            As[(s_kq * 4 + j) * ASTR + s_r + 16] = ((const float*)&a1)[j];
        }
#pragma unroll
        for (int hh = 0; hh < 8; ++hh) {
            int row = s_r + hh * 16;
            int half = row >> 6;
            int c = row & 63;
            float* wbase = &Ws[half * BKC * WSTR];
#pragma unroll
            for (int j = 0; j < 4; ++j)
                wbase[(s_kq * 4 + j) * WSTR + c] = ((const float*)&wv[hh])[j];
        }
        __syncthreads();

#pragma unroll
        for (int kk = 0; kk < BKC; ++kk) {
            float4 av = *(const float4*)&As[kk * ASTR + 4 * tb];
            float4 w0 = *(const float4*)&Ws[kk * WSTR + 4 * tn];
            float4 w1 = *(const float4*)&Ws[BKC * WSTR + kk * WSTR + 4 * tn];
#pragma unroll
            for (int i = 0; i < 4; ++i) {
                float a = ((const float*)&av)[i];
                acc[i][0] += a * w0.x; acc[i][1] += a * w0.y;
                acc[i][2] += a * w0.z; acc[i][3] += a * w0.w;
                acc[i][4] += a * w1.x; acc[i][5] += a * w1.y;
                acc[i][6] += a * w1.z; acc[i][7] += a * w1.w;
            }
        }
    }

    const int slice = sel * KS + ks;
    float* Cb = C + (size_t)slice * B32 * N;
    float4 bA = make_float4(0.f, 0.f, 0.f, 0.f), bB = bA;
    if (bias != nullptr && ks == 0) {
        bA = *(const float4*)&bias[n0 + 4 * tn];
        bB = *(const float4*)&bias[n0 + 64 + 4 * tn];
    }
#pragma unroll
    for (int i = 0; i < 4; ++i) {
        int b = 4 * tb + i;
        float4 vA = make_float4(acc[i][0] + bA.x, acc[i][1] + bA.y, acc[i][2] + bA.z, acc[i][3] + bA.w);
        float4 vB = make_float4(acc[i][4] + bB.x, acc[i][5] + bB.y, acc[i][6] + bB.z, acc[i][7] + bB.w);
        *(float4*)&Cb[(size_t)b * N + n0 + 4 * tn]       = vA;
        *(float4*)&Cb[(size_t)b * N + n0 + 64 + 4 * tn]  = vB;
    }
}

__global__ __launch_bounds__(256)
void gru_gates(const float* __restrict__ G,
               const float* __restrict__ bih, const float* __restrict__ bhh,
               float* __restrict__ hl)
{
    int idx = blockIdx.x * 256 + threadIdx.x;
    int b = idx >> 10, j = idx & 1023;
    float xr = 0, xz = 0, xn = 0, hr = 0, hz = 0, hn = 0;
#pragma unroll
    for (int ks = 0; ks < KS_GRU; ++ks) {
        const float* gx = G + ((size_t)ks * B32 + b) * 3072;
        const float* gh = G + ((size_t)(KS_GRU + ks) * B32 + b) * 3072;
        xr += gx[j];        xz += gx[1024 + j];  xn += gx[2048 + j];
        hr += gh[j];        hz += gh[1024 + j];  hn += gh[2048 + j];
    }
    float r = sigmoidf_(xr + bih[j] + hr + bhh[j]);
    float z = sigmoidf_(xz + bih[1024 + j] + hz + bhh[1024 + j]);
    float n = tanhf(xn + bih[2048 + j] + r * (hn + bhh[2048 + j]));
    float ho = hl[idx];
    hl[idx] = (1.0f - z) * n + z * ho;
}

__global__ __launch_bounds__(GEMM_THREADS)
void logits_kernel(const float* __restrict__ x,
                   const float* __restrict__ W, const float* __restrict__ bias,
                   float* __restrict__ out, int t, int T,
                   float* __restrict__ pval, int* __restrict__ pidx)
{
    __shared__ float As[BKC * ASTR];
    __shared__ float Ws[2 * BKC * WSTR];
    __shared__ float rval[B32 * 16];
    __shared__ int   ridx[B32 * 16];
    const int tid = threadIdx.x;
    const int n0 = blockIdx.x * TN;
    const int tb = tid & 7;
    const int tn = tid >> 3;
    const int s_kq = tid & 7;
    const int s_r  = tid >> 3;

    const float* arow0 = x + (size_t)s_r * KD;
    const float* arow1 = x + (size_t)(s_r + 16) * KD;
    const float* wrow  = W + (size_t)(n0 + s_r) * KD;

    float acc[4][8];
#pragma unroll
    for (int i = 0; i < 4; ++i)
#pragma unroll
        for (int j = 0; j < 8; ++j) acc[i][j] = 0.0f;

    for (int kc = 0; kc < KD; kc += BKC) {
        const int kb = kc + s_kq * 4;
        float4 a0 = *(const float4*)(arow0 + kb);
        float4 a1 = *(const float4*)(arow1 + kb);
        float4 wv[8];
#pragma unroll
        for (int hh = 0; hh < 8; ++hh)
            wv[hh] = *(const float4*)(wrow + (size_t)hh * 16 * KD + kb);

        __syncthreads();
#pragma unroll
        for (int j = 0; j < 4; ++j) {
            As[(s_kq * 4 + j) * ASTR + s_r]      = ((const float*)&a0)[j];
            As[(s_kq * 4 + j) * ASTR + s_r + 16] = ((const float*)&a1)[j];
        }
#pragma unroll
        for (int hh = 0; hh < 8; ++hh) {
            int row = s_r + hh * 16;
            int half = row >> 6;
            int c = row & 63;
            float* wbase = &Ws[half * BKC * WSTR];
#pragma unroll
            for (int j = 0; j < 4; ++j)
                wbase[(s_kq * 4 + j) * WSTR + c] = ((const float*)&wv[hh])[j];
        }
        __syncthreads();

#pragma unroll
        for (int kk = 0; kk < BKC; ++kk) {
            float4 av = *(const float4*)&As[kk * ASTR + 4 * tb];
            float4 w0 = *(const float4*)&Ws[kk * WSTR + 4 * tn];
            float4 w1 = *(const float4*)&Ws[BKC * WSTR + kk * WSTR + 4 * tn];
#pragma unroll
            for (int i = 0; i < 4; ++i) {
                float a = ((const float*)&av)[i];
                acc[i][0] += a * w0.x; acc[i][1] += a * w0.y;
                acc[i][2] += a * w0.z; acc[i][3] += a * w0.w;
                acc[i][4] += a * w1.x; acc[i][5] += a * w1.y;
                acc[i][6] += a * w1.z; acc[i][7] += a * w1.w;
            }
        }
    }

    float4 bA = *(const float4*)&bias[n0 + 4 * tn];
    float4 bB = *(const float4*)&bias[n0 + 64 + 4 * tn];

    float bestv[4]; int besti[4];
#pragma unroll
    for (int i = 0; i < 4; ++i) { bestv[i] = -INFINITY; besti[i] = INT_MAX; }

#pragma unroll
    for (int i = 0; i < 4; ++i) {
        int b = 4 * tb + i;
        float* orow = out + ((size_t)b * T + t) * VOC;
        float4 vA = make_float4(acc[i][0] + bA.x, acc[i][1] + bA.y, acc[i][2] + bA.z, acc[i][3] + bA.w);
        float4 vB = make_float4(acc[i][4] + bB.x, acc[i][5] + bB.y, acc[i][6] + bB.z, acc[i][7] + bB.w);
        *(float4*)&orow[n0 + 4 * tn]      = vA;
        *(float4*)&orow[n0 + 64 + 4 * tn] = vB;
#pragma unroll
        for (int j = 0; j < 4; ++j) {
            float v = ((const float*)&vA)[j]; int c = n0 + 4 * tn + j;
            if (v > bestv[i] || (v == bestv[i] && c < besti[i])) { bestv[i] = v; besti[i] = c; }
        }
#pragma unroll
        for (int j = 0; j < 4; ++j) {
            float v = ((const float*)&vB)[j]; int c = n0 + 64 + 4 * tn + j;
            if (v > bestv[i] || (v == bestv[i] && c < besti[i])) { bestv[i] = v; besti[i] = c; }
        }
    }
#pragma unroll
    for (int i = 0; i < 4; ++i) {
        rval[(4 * tb + i) * 16 + tn] = bestv[i];
        ridx[(4 * tb + i) * 16 + tn] = besti[i];
    }
    __syncthreads();
    if (tid < B32) {
        int b = tid;
        float bv = -INFINITY; int bi = INT_MAX;
        for (int q = 0; q < 16; ++q) {
            float v = rval[b * 16 + q]; int ii = ridx[b * 16 + q];
            if (v > bv || (v == bv && ii < bi)) { bv = v; bi = ii; }
        }
        pval[(size_t)blockIdx.x * B32 + b] = bv;
        pidx[(size_t)blockIdx.x * B32 + b] = bi;
    }
}

__global__ __launch_bounds__(256)
void amax_final(const float* __restrict__ pval, const int* __restrict__ pidx,
                int nblk, int* __restrict__ tokens)
{
    int tid = threadIdx.x;
    int b = tid >> 3, l8 = tid & 7;
    float bv = -INFINITY; int bi = INT_MAX;
    for (int q = l8; q < nblk; q += 8) {
        float v = pval[(size_t)q * B32 + b]; int ii = pidx[(size_t)q * B32 + b];
        if (v > bv || (v == bv && ii < bi)) { bv = v; bi = ii; }
    }
#pragma unroll
    for (int off = 1; off < 8; off <<= 1) {
        float ov = __shfl_xor(bv, off);
        int   oi = __shfl_xor(bi, off);
        if (ov > bv || (ov == bv && oi < bi)) { bv = ov; bi = oi; }
    }
    if (l8 == 0) tokens[b] = bi;
}

// ---------------- host ----------------
extern "C" void kernel_launch(void* const* d_in, const int* in_sizes, int n_in,
                              void* d_out, int out_size, void* d_ws, size_t ws_size,
                              hipStream_t stream)
{
    const float* z    = (const float*)d_in[0];
    const float* emb  = (const float*)d_in[1];
    const float* wlat = (const float*)d_in[2];
    const float* blat = (const float*)d_in[3];
    const float* wih  = (const float*)d_in[4];
    const float* whh  = (const float*)d_in[5];
    const float* bih  = (const float*)d_in[6];
    const float* bhh  = (const float*)d_in[7];
    const float* fcw  = (const float*)d_in[8];
    const float* fcb  = (const float*)d_in[9];
    float* out = (float*)d_out;
    const int T = out_size / (B32 * VOC);   // 128

    const size_t NEED = 152000000;
    if (ws_size >= NEED) {
        char* p = (char*)d_ws;
        auto take = [&](size_t bytes) { char* r = p; p += (bytes + 255) & ~(size_t)255; return r; };
        unsigned short* fcwPh = (unsigned short*)take((size_t)VOC * KD * 2);
        unsigned short* wihPh = (unsigned short*)take((size_t)NL * 3 * KD * KD * 2);
        unsigned short* wihPl = (unsigned short*)take((size_t)NL * 3 * KD * KD * 2);
        unsigned short* whhPh = (unsigned short*)take((size_t)NL * 3 * KD * KD * 2);
        unsigned short* whhPl = (unsigned short*)take((size_t)NL * 3 * KD * KD * 2);
        unsigned short* hPh   = (unsigned short*)take((size_t)NL * B32 * KD * 2);
        unsigned short* hPl   = (unsigned short*)take((size_t)NL * B32 * KD * 2);
        unsigned short* xPh   = (unsigned short*)take((size_t)B32 * KD * 2);
        unsigned short* xPl   = (unsigned short*)take((size_t)B32 * KD * 2);
        float* Gx  = (float*)take((size_t)128 * 3 * 1024 * 4);
        float* Ggh = (float*)take((size_t)NL * 128 * 3 * 1024 * 4);
        float* h32 = (float*)take((size_t)B32 * NL * KD * 4);
        unsigned long long* wbuf = (unsigned long long*)take(B32 * 8);
        unsigned* wn = (unsigned*)take(256);

        hipMemsetAsync(wbuf, 0, B32 * 8, stream);
        hipMemsetAsync(wn, 0, 4, stream);

        // one-time packing (fcw hi-only; GRU weights hi+lo) + column-norm bound
        {
            long nt_fc = VOC / 32;
            long nt_g  = (long)NL * 3 * KD / 32;
            pack_w<<<(unsigned)((nt_fc * 4096 + 255) / 256), 256, 0, stream>>>(fcw, fcwPh, nullptr, nt_fc);
            pack_w<<<(unsigned)((nt_g * 4096 + 255) / 256), 256, 0, stream>>>(wih, wihPh, wihPl, nt_g);
            pack_w<<<(unsigned)((nt_g * 4096 + 255) / 256), 256, 0, stream>>>(whh, whhPh, whhPl, nt_g);
            wnorm_k<<<VOC / 64, 256, 0, stream>>>(fcw, wn);
        }

        // hidden init (fp32), then pack the 3 [32x1024] planes
        gemm_k1024<<<dim3(NL * KD / TN, 1), GEMM_THREADS, 0, stream>>>(
            z, nullptr, nullptr, nullptr, 0, wlat, nullptr, blat, h32, NL * KD, 1);
        pack_w<<<(unsigned)((3L * 4096 + 255) / 256), 256, 0, stream>>>(h32, hPh, hPl, 3);

        const size_t PL = (size_t)B32 * KD;
        const size_t WL = (size_t)3 * KD * KD;
        for (int t = 0; t < T; ++t) {
            // packed: argmax-fix(t-1) + emb gather/pack (32 blocks)  ||  gh all layers (384 blocks)
            fix_gh<<<B32 + NL * 128, 256, 0, stream>>>(
                out, t - 1, T, hPh, hPl, fcw, fcb, wn, wbuf,
                emb, xPh, xPl, whhPh, whhPl, Ggh, t > 0 ? 1 : 0);

            for (int l = 0; l < NL; ++l) {
                const unsigned short* xh = (l == 0) ? xPh : hPh + (size_t)(l - 1) * PL;
                const unsigned short* xl = (l == 0) ? xPl : hPl + (size_t)(l - 1) * PL;
                gru_gx<<<128, 192, 0, stream>>>(
                    xh, xl,
                    wihPh + (size_t)l * WL, wihPl + (size_t)l * WL, Gx);
                gru_gates3<<<128, 256, 0, stream>>>(
                    Gx, Ggh + (size_t)l * 128 * 3 * 1024,
                    bih + (size_t)l * 3 * KD, bhh + (size_t)l * 3 * KD,
                    hPh + (size_t)l * PL, hPl + (size_t)l * PL);
            }
            logits6<<<250, 256, 0, stream>>>(
                hPh + 2 * PL, hPl + 2 * PL, fcwPh, fcb, out, t, T, wbuf);
        }
    } else {
        // fallback: round-1 fp32 path
        float* h      = (float*)d_ws;
        float* G      = h + (size_t)B32 * NL * HID;
        float* pval   = G + (size_t)2 * KS_GRU * B32 * NL * HID;
        int*   pidx   = (int*)(pval + (VOC / TN) * B32);
        int*   tokens = (int*)(pidx + (VOC / TN) * B32);

        hipMemsetAsync(tokens, 0, B32 * sizeof(int), stream);

        gemm_k1024<<<dim3(NL * HID / TN, 1), GEMM_THREADS, 0, stream>>>(
            z, nullptr, nullptr, nullptr, 0, wlat, nullptr, blat, h, NL * HID, 1);

        for (int t = 0; t < T; ++t) {
            for (int l = 0; l < NL; ++l) {
                const float* xA = (l == 0) ? nullptr : (h + (size_t)(l - 1) * B32 * HID);
                dim3 gg((NL * HID / TN) * KS_GRU, 2);
                gemm_k1024<<<gg, GEMM_THREADS, 0, stream>>>(
                    xA, h + (size_t)l * B32 * HID, emb, tokens, (l == 0) ? 1 : 0,
                    wih + (size_t)l * NL * HID * KD, whh + (size_t)l * NL * HID * KD,
                    nullptr, G, NL * HID, KS_GRU);
                gru_gates<<<B32 * HID / 256, 256, 0, stream>>>(
                    G, bih + (size_t)l * NL * HID, bhh + (size_t)l * NL * HID,
                    h + (size_t)l * B32 * HID);
            }
            logits_kernel<<<VOC / TN, GEMM_THREADS, 0, stream>>>(
                h + (size_t)2 * B32 * HID, fcw, fcb, out, t, T, pval, pidx);
            amax_final<<<1, 256, 0, stream>>>(pval, pidx, VOC / TN, tokens);
        }
    }
}